// Round 18
// baseline (111.014 us; speedup 1.0000x reference)
//
#include <hip/hip_runtime.h>
#include <math.h>

#define HH 512
#define WW 512
#define HB 64        // band height (8 bands per plane -> grid 992)
#define KR 4         // output rows per group
#define SUB 132      // uint2 slots per sub-array: 2+128+2 (halo+cols);
                     // 2*132 mod 32 == 8 -> write banks s*8+{0..14}: every
                     // bank exactly 2-way per 32-lane phase = FREE (m136).
#define ROWU2 (4 * SUB)     // 528 uint2 per row-tile
#define TILEU2 (4 * ROWU2)  // 2112 uint2 = 16896 B total (single buffer)

// R18 = R17 + q-cached register ring. R17 post-mortem: runtime ~= SUM of pipe
// times (VALU ~43us + LDS ~22 + HBM ~24 ~= 92.5 observed); VALU largest.
// q2=p^2+t^2, q3=p*t were recomputed in every group an input row touches
// (~3.5x): cache {q2,q3} in the ring as v2f, computed once per row at fold
// time. -7.5 inst/pt (~9% of VALU) for +~20 VGPR (56 -> ~80 << 128 cliff).
// Ring update order per group: consume (VACC) -> shift 0..5 <- 4..9 -> fold
// new rows into 6..9 (shift reads old 4,5 before any overwrite: safe).
// All else R16/R17-proven: f16 tile (absmax 0.0039 stable), SUB=132 banking
// (conflicts=0), imm-offset b64 taps, light lgkm barriers, 17KB tile.

typedef float v2f __attribute__((ext_vector_type(2)));
typedef _Float16 h2 __attribute__((ext_vector_type(2)));

__device__ __forceinline__ void bar_lgkm() {
  asm volatile("s_waitcnt lgkmcnt(0)" ::: "memory");
  __builtin_amdgcn_s_barrier();
  __builtin_amdgcn_sched_barrier(0);
}

__device__ __forceinline__ unsigned pk16(float a, float b) {
  return __builtin_bit_cast(unsigned, __builtin_amdgcn_cvt_pkrtz(a, b));
}

__global__ __launch_bounds__(512, 1)
void ssim_main(const float* __restrict__ Pg, const float* __restrict__ Tg,
               float* __restrict__ partial) {
  __shared__ __align__(16) uint2 S2[TILEU2];   // 16896 B
  __shared__ float wsum[8];

  const int tid = threadIdx.x;            // vertical pass: column 0..511
  const int blk = blockIdx.x;
  const int plane = blk >> 3;
  const int band  = blk & 7;
  const int o0 = band * HB;               // first output row of band
  const float* __restrict__ P = Pg + (size_t)plane * (HH * WW);
  const float* __restrict__ T = Tg + (size_t)plane * (HH * WW);

  {
    const uint2 z = make_uint2(0u, 0u);
    for (int idx = tid; idx < TILEU2; idx += 512) S2[idx] = z;
  }

  float w[11];
  {
    double g[11], s = 0.0;
#pragma unroll
    for (int k = 0; k < 11; ++k) {
      double c = (double)(k - 5);
      g[k] = exp(-c * c / 4.5);
      s += g[k];
    }
#pragma unroll
    for (int k = 0; k < 11; ++k)
      w[k] = __uint_as_float(__builtin_amdgcn_readfirstlane(
                 __float_as_uint((float)(g[k] / s))));
  }
  h2 wh[11];
#pragma unroll
  for (int k = 0; k < 11; ++k) {
    const _Float16 hw = (_Float16)w[k];
    wh[k][0] = hw; wh[k][1] = hw;
  }

  float sum = 0.f;
  const int jr = tid >> 7;                // H-pass: row within group (0..3)
  const int q  = tid & 127;               // H-pass: cols 4q..4q+3
  uint2* const rdbase = &S2[jr * ROWU2 + q + 2];
  uint2* const wrbase = &S2[(tid & 3) * SUB + (tid >> 2) + 2];

  // q-cached rotating ring: rpt[i]={p,t}, rq[i]={p^2+t^2,p*t} for input row
  // rbase+i (i=0..9); pn/tn[4] raw rows rbase+10..13 in flight.
  v2f rpt[10], rq[10];
  float pn[4], tn[4];
#pragma unroll
  for (int i = 0; i < 10; ++i) {
    const int r = o0 - 5 + i;
    const bool v = (r >= 0);
    const float p = v ? P[(size_t)r * WW + tid] : 0.f;
    const float t = v ? T[(size_t)r * WW + tid] : 0.f;
    rpt[i][0] = p;                 rpt[i][1] = t;
    rq[i][0]  = fmaf(t, t, p * p); rq[i][1]  = p * t;
  }
#pragma unroll
  for (int i = 0; i < 4; ++i) {
    const int r = o0 + 5 + i;             // always in [5, 461]
    pn[i] = P[(size_t)r * WW + tid];
    tn[i] = T[(size_t)r * WW + tid];
  }

#define VACC(RI, PTV, QV) {                                                \
      _Pragma("unroll")                                                   \
      for (int j = 0; j < KR; ++j) {                                      \
        if ((RI) - j >= 0 && (RI) - j <= 10) {                            \
          const float wk = w[(RI) - j];                                   \
          const v2f wv = {wk, wk};                                        \
          apt[j] = __builtin_elementwise_fma(wv, (PTV), apt[j]);          \
          asq[j] = __builtin_elementwise_fma(wv, (QV),  asq[j]);          \
        }                                                                 \
      }                                                                   \
    }

#define VBLOCK(G) {                                                        \
    { const v2f z = {0.f, 0.f};                                            \
      _Pragma("unroll")                                                    \
      for (int j = 0; j < KR; ++j) { apt[j] = z; asq[j] = z; } }           \
    _Pragma("unroll")                                                      \
    for (int ri = 0; ri < 10; ++ri) VACC(ri, rpt[ri], rq[ri]);             \
    v2f fpt[4], fq[4];                                                     \
    _Pragma("unroll")                                                      \
    for (int i = 0; i < 4; ++i) {                                          \
      const float p_ = pn[i], t_ = tn[i];                                  \
      fpt[i][0] = p_;                  fpt[i][1] = t_;                     \
      fq[i][0]  = fmaf(t_, t_, p_ * p_); fq[i][1] = p_ * t_;               \
      VACC(10 + i, fpt[i], fq[i]);                                         \
    }                                                                      \
    /* shift 0..5 <- 4..9 (reads old 4..9), then fold new rows to 6..9 */  \
    _Pragma("unroll")                                                      \
    for (int i = 0; i < 6; ++i) { rpt[i] = rpt[i + 4]; rq[i] = rq[i + 4]; }\
    _Pragma("unroll")                                                      \
    for (int i = 0; i < 4; ++i) { rpt[6 + i] = fpt[i]; rq[6 + i] = fq[i]; }\
    { const int prow = o0 + (G) + 9;                                       \
      if (prow + 3 < HH) {                                                 \
        _Pragma("unroll")                                                  \
        for (int i = 0; i < 4; ++i) {                                      \
          pn[i] = P[(size_t)(prow + i) * WW + tid];                        \
          tn[i] = T[(size_t)(prow + i) * WW + tid];                        \
        }                                                                  \
      } else {                                                             \
        _Pragma("unroll")                                                  \
        for (int i = 0; i < 4; ++i) {                                      \
          const int r = prow + i;                                          \
          const bool v = r < HH;                                           \
          pn[i] = v ? P[(size_t)r * WW + tid] : 0.f;                       \
          tn[i] = v ? T[(size_t)r * WW + tid] : 0.f;                       \
        }                                                                  \
      } }                                                                  \
  }

  v2f apt[KR], asq[KR];
  VBLOCK(0)                               // V for group 0; prefetch group 1

  for (int g = 0; g < HB; g += KR) {      // 16 groups of 4 output rows
    bar_lgkm();        // prior group's H reads done (g=0: zero-init visible)
#pragma unroll
    for (int j = 0; j < KR; ++j)
      wrbase[j * ROWU2] = make_uint2(pk16(apt[j][0], apt[j][1]),
                                     pk16(asq[j][0], asq[j][1]));
    bar_lgkm();        // stage visible to all waves
    h2 hpt[4], hsq[4];
    { const h2 z = {(_Float16)0.f, (_Float16)0.f};
#pragma unroll
      for (int m = 0; m < 4; ++m) { hpt[m] = z; hsq[m] = z; } }
#pragma unroll
    for (int k = 0; k < 14; ++k) {
      const int d = k - 5;
      const int s = d & 3;
      const int o = (d - s) >> 2;
      const uint2 vv = rdbase[s * SUB + o];
      const h2 va = __builtin_bit_cast(h2, vv.x);
      const h2 vb = __builtin_bit_cast(h2, vv.y);
#pragma unroll
      for (int m = 0; m < 4; ++m)
        if (k - m >= 0 && k - m <= 10) {
          hpt[m] = __builtin_elementwise_fma(wh[k - m], va, hpt[m]);
          hsq[m] = __builtin_elementwise_fma(wh[k - m], vb, hsq[m]);
        }
    }
#pragma unroll
    for (int m = 0; m < 4; ++m) {
      const float hmp = (float)hpt[m][0], hmt = (float)hpt[m][1];
      const float s2f = (float)hsq[m][0], scf = (float)hsq[m][1];
      const float mp2 = hmp * hmp, mt2 = hmt * hmt, mct = hmp * hmt;
      const float ssum = fmaxf(s2f - mp2 - mt2, 0.f);
      const float scv = scf - mct;
      const float num = fmaf(2.f, mct, 1.0e-4f) * fmaf(2.f, scv, 9.0e-4f);
      const float den = (mp2 + mt2 + 1.0e-4f) * (ssum + 9.0e-4f);
      sum += num * __builtin_amdgcn_rcpf(den);
    }
    if (g + KR < HB) VBLOCK(g + KR)       // V for next group (reg-only)
  }
#undef VBLOCK
#undef VACC

#pragma unroll
  for (int off = 32; off > 0; off >>= 1) sum += __shfl_down(sum, off, 64);
  if ((tid & 63) == 0) wsum[tid >> 6] = sum;
  __syncthreads();
  if (tid == 0) {
    float s = 0.f;
#pragma unroll
    for (int k2 = 0; k2 < 8; ++k2) s += wsum[k2];
    partial[blk] = s;
  }
}

__global__ void ssim_fin(const float* __restrict__ partial,
                         float* __restrict__ out, int n) {
  __shared__ double ws[4];
  double s = 0.0;
  for (int idx = threadIdx.x; idx < n; idx += 256) s += (double)partial[idx];
#pragma unroll
  for (int off = 32; off > 0; off >>= 1) s += __shfl_down(s, off, 64);
  if ((threadIdx.x & 63) == 0) ws[threadIdx.x >> 6] = s;
  __syncthreads();
  if (threadIdx.x == 0) {
    double tt = ws[0] + ws[1] + ws[2] + ws[3];
    out[0] = (float)(1.0 - tt / 32505856.0);
  }
}

extern "C" void kernel_launch(void* const* d_in, const int* in_sizes, int n_in,
                              void* d_out, int out_size, void* d_ws, size_t ws_size,
                              hipStream_t stream) {
  const float* pred = (const float*)d_in[0];
  const float* tgt  = (const float*)d_in[1];
  float* out        = (float*)d_out;
  float* partial    = (float*)d_ws;   // 992 floats of scratch

  ssim_main<<<dim3(992), dim3(512), 0, stream>>>(pred, tgt, partial);
  ssim_fin<<<dim3(1), dim3(256), 0, stream>>>(partial, out, 992);
}

// Round 19
// 93.749 us; speedup vs baseline: 1.1842x; 1.1842x over previous
//
#include <hip/hip_runtime.h>
#include <math.h>

#define HH 512
#define WW 512
#define HB 32        // band height (16 bands per plane -> grid 1984)
#define KR 4         // output rows per group
#define SUB 132      // uint2 slots per sub-array: 2+128+2 (halo+cols);
                     // 2*132 mod 32 == 8 -> write banks s*8+{0..14}: every
                     // bank exactly 2-way per 32-lane phase = FREE (m136).
#define ROWU2 (4 * SUB)     // 528 uint2 per row-tile
#define TILEU2 (4 * ROWU2)  // 2112 uint2 = 16896 B total (single buffer)

// R19 = R17 (92.5us best; VGPR 56, conflicts 0, f16 tile absmax 0.0039)
// with HB 64->32. R18 lesson: the occupancy cliff is at VGPR=64 (m69) --
// the q-cache's +12 VGPR halved occupancy and cost 20%; reverted.
// HB=32 doubles the grid (992->1984 blocks, ~7.8 ready blocks/CU) so the
// scheduler can backfill band-boundary tails and smooth imbalance; cost is
// +13% vertical-halo fetch (~+3us at 15% HBM util).
// Structure per group (R17-proven): [bar | 4 ds_write stage | bar | H(g) +
// SSIM + V(g+1) + prefetch], light lgkm-only barriers keep the 4-row
// prefetch in flight across the barrier pair.

typedef float v2f __attribute__((ext_vector_type(2)));
typedef _Float16 h2 __attribute__((ext_vector_type(2)));

__device__ __forceinline__ void bar_lgkm() {
  asm volatile("s_waitcnt lgkmcnt(0)" ::: "memory");
  __builtin_amdgcn_s_barrier();
  __builtin_amdgcn_sched_barrier(0);
}

__device__ __forceinline__ unsigned pk16(float a, float b) {
  return __builtin_bit_cast(unsigned, __builtin_amdgcn_cvt_pkrtz(a, b));
}

__global__ __launch_bounds__(512, 1)
void ssim_main(const float* __restrict__ Pg, const float* __restrict__ Tg,
               float* __restrict__ partial) {
  __shared__ __align__(16) uint2 S2[TILEU2];   // 16896 B
  __shared__ float wsum[8];

  const int tid = threadIdx.x;            // vertical pass: column 0..511
  const int blk = blockIdx.x;
  const int plane = blk >> 4;             // 16 bands per plane
  const int band  = blk & 15;
  const int o0 = band * HB;               // first output row of band
  const float* __restrict__ P = Pg + (size_t)plane * (HH * WW);
  const float* __restrict__ T = Tg + (size_t)plane * (HH * WW);

  // zero tile once: halo slots (0,1,130,131 per sub-array) must stay 0
  // forever; interior slots 2..129 are fully overwritten every group.
  {
    const uint2 z = make_uint2(0u, 0u);
    for (int idx = tid; idx < TILEU2; idx += 512) S2[idx] = z;
  }

  // Gaussian weights, computed in double then rounded to f32 (matches jnp f32)
  float w[11];
  {
    double g[11], s = 0.0;
#pragma unroll
    for (int k = 0; k < 11; ++k) {
      double c = (double)(k - 5);
      g[k] = exp(-c * c / 4.5);
      s += g[k];
    }
#pragma unroll
    for (int k = 0; k < 11; ++k)
      w[k] = __uint_as_float(__builtin_amdgcn_readfirstlane(
                 __float_as_uint((float)(g[k] / s))));
  }
  // f16 weight pairs for the packed H-pass
  h2 wh[11];
#pragma unroll
  for (int k = 0; k < 11; ++k) {
    const _Float16 hw = (_Float16)w[k];
    wh[k][0] = hw; wh[k][1] = hw;
  }

  float sum = 0.f;
  const int jr = tid >> 7;                // H-pass: row within group (0..3)
  const int q  = tid & 127;               // H-pass: cols 4q..4q+3
  uint2* const rdbase = &S2[jr * ROWU2 + q + 2];
  uint2* const wrbase = &S2[(tid & 3) * SUB + (tid >> 2) + 2];

  // ---- rotating register ring (R12-proven): pr/tr[i] = input row rbase+i
  // (i=0..9); pn/tn = rows rbase+10..13 in flight. rbase = o0 + g - 5.
  float pr[10], tr[10], pn[4], tn[4];
#pragma unroll
  for (int i = 0; i < 10; ++i) {
    const int r = o0 - 5 + i;
    const bool v = (r >= 0);              // r <= o0+4 <= 484 < HH always
    pr[i] = v ? P[(size_t)r * WW + tid] : 0.f;
    tr[i] = v ? T[(size_t)r * WW + tid] : 0.f;
  }
#pragma unroll
  for (int i = 0; i < 4; ++i) {
    const int r = o0 + 5 + i;             // always in [5, 493]
    pn[i] = P[(size_t)r * WW + tid];
    tn[i] = T[(size_t)r * WW + tid];
  }

#define VACC(RI, PV, TV) {                                                 \
      const float p_ = (PV), t_ = (TV);                                   \
      const v2f pt  = {p_, t_};                                           \
      const v2f q23 = {fmaf(t_, t_, p_ * p_), p_ * t_};                   \
      _Pragma("unroll")                                                   \
      for (int j = 0; j < KR; ++j) {                                      \
        if ((RI) - j >= 0 && (RI) - j <= 10) {                            \
          const float wk = w[(RI) - j];                                   \
          const v2f wv = {wk, wk};                                        \
          apt[j] = __builtin_elementwise_fma(wv, pt,  apt[j]);            \
          asq[j] = __builtin_elementwise_fma(wv, q23, asq[j]);            \
        }                                                                 \
      }                                                                   \
    }

// VBLOCK(G): vertical sums for output rows G..G+3 into apt/asq (from ring),
// then rotate ring by 4 and issue the prefetch for rows o0+G+9..+12.
#define VBLOCK(G) {                                                        \
    { const v2f z = {0.f, 0.f};                                            \
      _Pragma("unroll")                                                    \
      for (int j = 0; j < KR; ++j) { apt[j] = z; asq[j] = z; } }           \
    _Pragma("unroll")                                                      \
    for (int ri = 0; ri < 10; ++ri) VACC(ri, pr[ri], tr[ri]);              \
    _Pragma("unroll")                                                      \
    for (int i = 0; i < 4; ++i) VACC(10 + i, pn[i], tn[i]);                \
    _Pragma("unroll")                                                      \
    for (int i = 0; i < 6; ++i) { pr[i] = pr[i + 4]; tr[i] = tr[i + 4]; }  \
    _Pragma("unroll")                                                      \
    for (int i = 0; i < 4; ++i) { pr[6 + i] = pn[i]; tr[6 + i] = tn[i]; }  \
    { const int prow = o0 + (G) + 9;                                       \
      if (prow + 3 < HH) {                                                 \
        _Pragma("unroll")                                                  \
        for (int i = 0; i < 4; ++i) {                                      \
          pn[i] = P[(size_t)(prow + i) * WW + tid];                        \
          tn[i] = T[(size_t)(prow + i) * WW + tid];                        \
        }                                                                  \
      } else {                                                             \
        _Pragma("unroll")                                                  \
        for (int i = 0; i < 4; ++i) {                                      \
          const int r = prow + i;                                          \
          const bool v = r < HH;                                           \
          pn[i] = v ? P[(size_t)r * WW + tid] : 0.f;                       \
          tn[i] = v ? T[(size_t)r * WW + tid] : 0.f;                       \
        }                                                                  \
      } }                                                                  \
  }

  v2f apt[KR], asq[KR];
  VBLOCK(0)                               // V for group 0; prefetch group 1

  for (int g = 0; g < HB; g += KR) {      // 8 groups of 4 output rows
    bar_lgkm();        // prior group's H reads done (g=0: zero-init visible)
#pragma unroll
    for (int j = 0; j < KR; ++j)
      wrbase[j * ROWU2] = make_uint2(pk16(apt[j][0], apt[j][1]),
                                     pk16(asq[j][0], asq[j][1]));
    bar_lgkm();        // stage visible to all waves
    // ---- big region: H(g) + SSIM + V(g+1) + prefetch (reg-only) ----
    h2 hpt[4], hsq[4];
    { const h2 z = {(_Float16)0.f, (_Float16)0.f};
#pragma unroll
      for (int m = 0; m < 4; ++m) { hpt[m] = z; hsq[m] = z; } }
#pragma unroll
    for (int k = 0; k < 14; ++k) {
      const int d = k - 5;
      const int s = d & 3;
      const int o = (d - s) >> 2;
      const uint2 vv = rdbase[s * SUB + o];
      const h2 va = __builtin_bit_cast(h2, vv.x);
      const h2 vb = __builtin_bit_cast(h2, vv.y);
#pragma unroll
      for (int m = 0; m < 4; ++m)
        if (k - m >= 0 && k - m <= 10) {
          hpt[m] = __builtin_elementwise_fma(wh[k - m], va, hpt[m]);
          hsq[m] = __builtin_elementwise_fma(wh[k - m], vb, hsq[m]);
        }
    }
#pragma unroll
    for (int m = 0; m < 4; ++m) {
      const float hmp = (float)hpt[m][0], hmt = (float)hpt[m][1];
      const float s2f = (float)hsq[m][0], scf = (float)hsq[m][1];
      const float mp2 = hmp * hmp, mt2 = hmt * hmt, mct = hmp * hmt;
      const float ssum = fmaxf(s2f - mp2 - mt2, 0.f);
      const float scv = scf - mct;
      const float num = fmaf(2.f, mct, 1.0e-4f) * fmaf(2.f, scv, 9.0e-4f);
      const float den = (mp2 + mt2 + 1.0e-4f) * (ssum + 9.0e-4f);
      sum += num * __builtin_amdgcn_rcpf(den);
    }
    if (g + KR < HB) VBLOCK(g + KR)       // V for next group (reg-only)
  }
#undef VBLOCK
#undef VACC

  // block reduction of ssim partial sum
#pragma unroll
  for (int off = 32; off > 0; off >>= 1) sum += __shfl_down(sum, off, 64);
  if ((tid & 63) == 0) wsum[tid >> 6] = sum;
  __syncthreads();
  if (tid == 0) {
    float s = 0.f;
#pragma unroll
    for (int k2 = 0; k2 < 8; ++k2) s += wsum[k2];
    partial[blk] = s;
  }
}

__global__ void ssim_fin(const float* __restrict__ partial,
                         float* __restrict__ out, int n) {
  __shared__ double ws[4];
  double s = 0.0;
  for (int idx = threadIdx.x; idx < n; idx += 256) s += (double)partial[idx];
#pragma unroll
  for (int off = 32; off > 0; off >>= 1) s += __shfl_down(s, off, 64);
  if ((threadIdx.x & 63) == 0) ws[threadIdx.x >> 6] = s;
  __syncthreads();
  if (threadIdx.x == 0) {
    double tt = ws[0] + ws[1] + ws[2] + ws[3];
    out[0] = (float)(1.0 - tt / 32505856.0);
  }
}

extern "C" void kernel_launch(void* const* d_in, const int* in_sizes, int n_in,
                              void* d_out, int out_size, void* d_ws, size_t ws_size,
                              hipStream_t stream) {
  const float* pred = (const float*)d_in[0];
  const float* tgt  = (const float*)d_in[1];
  float* out        = (float*)d_out;
  float* partial    = (float*)d_ws;   // 1984 floats of scratch

  ssim_main<<<dim3(1984), dim3(512), 0, stream>>>(pred, tgt, partial);
  ssim_fin<<<dim3(1), dim3(256), 0, stream>>>(partial, out, 1984);
}